// Round 4
// baseline (194.750 us; speedup 1.0000x reference)
//
#include <hip/hip_runtime.h>
#include <math.h>

#define IMG_H 512
#define IMG_W 512
#define HWSZ (IMG_H * IMG_W)
#define BATCH 32

// paired activation layout: element (k, b) lives at (k>>1)*64 + b*2 + (k&1)
// so one float2 per lane (b) covers k and k+1 -> 256B coalesced wave load.
__device__ __forceinline__ size_t xidx(int k, int b) {
    return (size_t)(k >> 1) * 64 + b * 2 + (k & 1);
}

// ---------------------------------------------------------------------------
// Kernel 1: blocks 0..31  : full per-image histogram + normalize + paired write
//           blocks 32..63 : bias init of y1 (32768) and y2 (16384), paired
// ---------------------------------------------------------------------------
__global__ __launch_bounds__(1024) void hist_bias_k(const float* __restrict__ img,
                                                    float* __restrict__ histT,
                                                    const float* __restrict__ b1,
                                                    const float* __restrict__ b2,
                                                    float* __restrict__ y1,
                                                    float* __restrict__ y2)
{
    if (blockIdx.x >= 32) {
        const int t = (blockIdx.x - 32) * 1024 + threadIdx.x;   // [0, 32768)
        {
            const int o = ((t >> 6) << 1) | (t & 1);
            y1[t] = b1[o];
        }
        if (t < 16384) {
            const int o = ((t >> 6) << 1) | (t & 1);
            y2[t] = b2[o];
        }
        return;
    }

    const int b   = blockIdx.x;     // image index
    const int tid = threadIdx.x;    // downsampled pixel id 0..1023

    __shared__ float hh[3][1024];
    __shared__ float red[17];

    hh[0][tid] = 0.f;
    hh[1][tid] = 0.f;
    hh[2][tid] = 0.f;
    __syncthreads();

    // nearest-downsample: src index = 16*dst (512/32 == 16 exactly)
    const int py  = tid >> 5;
    const int pxi = tid & 31;
    const size_t base = (size_t)b * 3 * HWSZ + (size_t)(py * 16) * IMG_W + (size_t)(pxi * 16);

    const float r  = img[base];
    const float g  = img[base + HWSZ];
    const float bl = img[base + 2 * HWSZ];

    const bool valid = (r > 0.f) && (g > 0.f) && (bl > 0.f);

    // constants exactly as the reference (f64 arithmetic, then cast to f32)
    const float LOc = (float)(-3.2 - (6.4 / 256.0) * 0.5);
    const float HIc = (float)( 3.2 - (6.4 / 256.0) * 0.5);
    const float BWc = (float)(((3.2 - (6.4 / 256.0) * 0.5) - (-3.2 - (6.4 / 256.0) * 0.5)) / 32.0);

    if (valid) {
        const float w  = sqrtf(r * r + g * g + bl * bl);
        const float lr = logf(r);
        const float lg = logf(g);
        const float lb = logf(bl);

        float us[3] = { lr - lb, lg - lb, lb - lg };
        float vs[3] = { lr - lg, lg - lr, lb - lr };

        #pragma unroll
        for (int i = 0; i < 3; ++i) {
            const float U = us[i];
            const float V = vs[i];
            if (U >= LOc && U <= HIc && V >= LOc && V <= HIc) {
                int iu = (int)floorf((U - LOc) / BWc); iu = iu < 31 ? iu : 31;
                int iv = (int)floorf((V - LOc) / BWc); iv = iv < 31 ? iv : 31;
                atomicAdd(&hh[i][iu * 32 + iv], w);
            }
        }
    }
    __syncthreads();

    // per-channel sum + sqrt-normalize, write paired-transposed
    #pragma unroll
    for (int i = 0; i < 3; ++i) {
        float v = hh[i][tid];
        float t = v;
        #pragma unroll
        for (int off = 32; off; off >>= 1) t += __shfl_down(t, off);
        if ((tid & 63) == 0) red[tid >> 6] = t;
        __syncthreads();
        if (tid == 0) {
            float s = 0.f;
            #pragma unroll
            for (int j = 0; j < 16; ++j) s += red[j];
            red[16] = 1.0f / s;
        }
        __syncthreads();
        const float inv = red[16];
        histT[xidx(i * 1024 + tid, b)] = sqrtf(v * inv);
        __syncthreads();   // red[] reused next channel
    }
}

// ---------------------------------------------------------------------------
// GEMM: y[o][b] += sum_{k in chunk} x[k][b] * W[o][k]   (atomic split-K)
// Wave = 8 outputs x 32 batches x chunk C. b = lane&31 (halves duplicate).
// W addresses are wave-uniform (readfirstlane) -> scalar s_load path.
// x loads: one float2 per lane = 256B coalesced per 2 k's.
// RELU applies relu to x on load (previous layer stored pre-activation).
// ---------------------------------------------------------------------------
template <int K, int N, int S, bool RELU>
__global__ __launch_bounds__(256) void gemm_atomic_k(const float* __restrict__ xT,
                                                     const float* __restrict__ W,
                                                     float* __restrict__ y)
{
    constexpr int C  = K / S;
    constexpr int NG = N / 8;

    const int wave = (blockIdx.x * 256 + threadIdx.x) >> 6;
    const int lane = threadIdx.x & 63;
    const int b    = lane & 31;
    const int o0   = __builtin_amdgcn_readfirstlane((wave % NG) * 8);
    const int k0   = __builtin_amdgcn_readfirstlane((wave / NG) * C);

    const float* Wr[8];
    #pragma unroll
    for (int j = 0; j < 8; ++j) Wr[j] = W + (size_t)(o0 + j) * K + k0;

    const float2* xp = reinterpret_cast<const float2*>(xT + (size_t)k0 * BATCH) + b;

    float acc[8] = {0.f, 0.f, 0.f, 0.f, 0.f, 0.f, 0.f, 0.f};

    #pragma unroll 4
    for (int kk2 = 0; kk2 < C / 2; ++kk2) {
        float2 v = xp[kk2 * BATCH];
        if (RELU) { v.x = fmaxf(v.x, 0.f); v.y = fmaxf(v.y, 0.f); }
        #pragma unroll
        for (int j = 0; j < 8; ++j) {
            acc[j] = fmaf(v.x, Wr[j][2 * kk2],     acc[j]);
            acc[j] = fmaf(v.y, Wr[j][2 * kk2 + 1], acc[j]);
        }
    }

    if (lane < 32) {
        #pragma unroll
        for (int j = 0; j < 8; ++j)
            atomicAdd(&y[xidx(o0 + j, b)], acc[j]);
    }
}

// ---------------------------------------------------------------------------
// L3: block-local split-K. One block per 8-output group; 4 waves each take a
// 128-k chunk; LDS reduce; bias + ReLU; write out[b][o] directly.
// ---------------------------------------------------------------------------
template <int K, int N>
__global__ __launch_bounds__(256) void linear_out_k(const float* __restrict__ xT,
                                                    const float* __restrict__ W,
                                                    const float* __restrict__ bias,
                                                    float* __restrict__ out)
{
    constexpr int C = K / 4;                 // 128
    const int og   = blockIdx.x;             // 32 o-groups
    const int w    = threadIdx.x >> 6;
    const int lane = threadIdx.x & 63;
    const int b    = lane & 31;
    const int o0   = og * 8;
    const int k0   = __builtin_amdgcn_readfirstlane(w * C);

    const float* Wr[8];
    #pragma unroll
    for (int j = 0; j < 8; ++j) Wr[j] = W + (size_t)(o0 + j) * K + k0;

    const float2* xp = reinterpret_cast<const float2*>(xT + (size_t)k0 * BATCH) + b;

    float acc[8] = {0.f, 0.f, 0.f, 0.f, 0.f, 0.f, 0.f, 0.f};

    #pragma unroll 4
    for (int kk2 = 0; kk2 < C / 2; ++kk2) {
        float2 v = xp[kk2 * BATCH];
        v.x = fmaxf(v.x, 0.f); v.y = fmaxf(v.y, 0.f);
        #pragma unroll
        for (int j = 0; j < 8; ++j) {
            acc[j] = fmaf(v.x, Wr[j][2 * kk2],     acc[j]);
            acc[j] = fmaf(v.y, Wr[j][2 * kk2 + 1], acc[j]);
        }
    }

    __shared__ float part[4][8][32];
    if (lane < 32) {
        #pragma unroll
        for (int j = 0; j < 8; ++j) part[w][j][b] = acc[j];
    }
    __syncthreads();

    const int j  = threadIdx.x >> 5;         // output within group
    const int b2 = threadIdx.x & 31;         // batch
    float s = part[0][j][b2] + part[1][j][b2] + part[2][j][b2] + part[3][j][b2]
            + bias[o0 + j];
    out[b2 * N + o0 + j] = fmaxf(s, 0.f);
}

// ---------------------------------------------------------------------------
extern "C" void kernel_launch(void* const* d_in, const int* in_sizes, int n_in,
                              void* d_out, int out_size, void* d_ws, size_t ws_size,
                              hipStream_t stream)
{
    const float* img = (const float*)d_in[0];
    const float* W1  = (const float*)d_in[1];
    const float* b1  = (const float*)d_in[2];
    const float* W2  = (const float*)d_in[3];
    const float* b2  = (const float*)d_in[4];
    const float* W3  = (const float*)d_in[5];
    const float* b3  = (const float*)d_in[6];
    float* out = (float*)d_out;

    float* ws = (float*)d_ws;
    float* histT = ws;                      // [3072][32] paired
    float* y1    = histT + 3072 * BATCH;    // [1024][32] paired
    float* y2    = y1    + 1024 * BATCH;    // [512][32] paired

    // full hist (+ normalize + transpose) and bias init, one dispatch
    hist_bias_k<<<64, 1024, 0, stream>>>(img, histT, b1, b2, y1, y2);

    // L1: 3072 -> 1024   (2048 waves, atomic split-K 16)
    gemm_atomic_k<3072, 1024, 16, false><<<512, 256, 0, stream>>>(histT, W1, y1);
    // L2: 1024 -> 512    (1024 waves, atomic split-K 16)
    gemm_atomic_k<1024,  512, 16, true ><<<256, 256, 0, stream>>>(y1, W2, y2);
    // L3: 512 -> 256     (32 blocks, block-local split-K, writes out[b][o])
    linear_out_k<512, 256><<<32, 256, 0, stream>>>(y2, W3, b3, out);
}

// Round 5
// 191.914 us; speedup vs baseline: 1.0148x; 1.0148x over previous
//
#include <hip/hip_runtime.h>
#include <math.h>

#define IMG_H 512
#define IMG_W 512
#define HWSZ (IMG_H * IMG_W)
#define BATCH 32

// paired activation layout: element (k, b) lives at (k>>1)*64 + b*2 + (k&1)
// so one float2 per lane (b) covers k and k+1 -> 256B coalesced wave load.
__device__ __forceinline__ size_t xidx(int k, int b) {
    return (size_t)(k >> 1) * 64 + b * 2 + (k & 1);
}

// ---------------------------------------------------------------------------
// Kernel 1: blocks 0..127   = partial histograms (4 blocks/image, 1 px/thread)
//           blocks 128..319 = bias init of y1 (32768) and y2 (16384), paired
// ---------------------------------------------------------------------------
__global__ __launch_bounds__(256) void hist_part_k(const float* __restrict__ img,
                                                   float* __restrict__ hp,
                                                   const float* __restrict__ b1,
                                                   const float* __restrict__ b2,
                                                   float* __restrict__ y1,
                                                   float* __restrict__ y2)
{
    if (blockIdx.x >= 128) {
        const int t = (blockIdx.x - 128) * 256 + threadIdx.x;   // [0, 49152)
        if (t < 32768) {
            const int o = ((t >> 6) << 1) | (t & 1);
            y1[t] = b1[o];
        } else {
            const int u = t - 32768;
            const int o = ((u >> 6) << 1) | (u & 1);
            y2[u] = b2[o];
        }
        return;
    }

    const int img_i = blockIdx.x >> 2;
    const int blk   = blockIdx.x & 3;
    const int tid   = threadIdx.x;

    __shared__ float hh[3072];
    for (int i = tid; i < 3072; i += 256) hh[i] = 0.f;
    __syncthreads();

    const int p  = blk * 256 + tid;          // downsampled pixel id 0..1023
    const int py = p >> 5;
    const int px = p & 31;
    const size_t base = (size_t)img_i * 3 * HWSZ + (size_t)(py * 16) * IMG_W + (size_t)(px * 16);

    const float r  = img[base];
    const float g  = img[base + HWSZ];
    const float bl = img[base + 2 * HWSZ];

    const bool valid = (r > 0.f) && (g > 0.f) && (bl > 0.f);

    const float LOc = (float)(-3.2 - (6.4 / 256.0) * 0.5);
    const float HIc = (float)( 3.2 - (6.4 / 256.0) * 0.5);
    const float BWc = (float)(((3.2 - (6.4 / 256.0) * 0.5) - (-3.2 - (6.4 / 256.0) * 0.5)) / 32.0);

    if (valid) {
        const float w  = sqrtf(r * r + g * g + bl * bl);
        const float lr = logf(r);
        const float lg = logf(g);
        const float lb = logf(bl);

        float us[3] = { lr - lb, lg - lb, lb - lg };
        float vs[3] = { lr - lg, lg - lr, lb - lr };

        #pragma unroll
        for (int i = 0; i < 3; ++i) {
            const float U = us[i];
            const float V = vs[i];
            if (U >= LOc && U <= HIc && V >= LOc && V <= HIc) {
                int iu = (int)floorf((U - LOc) / BWc); iu = iu < 31 ? iu : 31;
                int iv = (int)floorf((V - LOc) / BWc); iv = iv < 31 ? iv : 31;
                atomicAdd(&hh[i * 1024 + iu * 32 + iv], w);
            }
        }
    }
    __syncthreads();

    float* outp = hp + (size_t)blockIdx.x * 3072;
    for (int i = tid; i < 3072; i += 256) outp[i] = hh[i];
}

// ---------------------------------------------------------------------------
// Kernel 2: per-image normalize + sqrt, write paired-transposed histT.
// One block (1024 threads) per image. All 3 channel reductions done
// concurrently (one barrier round, not three).
// ---------------------------------------------------------------------------
__global__ __launch_bounds__(1024) void hist_norm_k(const float* __restrict__ hp,
                                                    float* __restrict__ histT)
{
    const int img_i = blockIdx.x;
    const int tid   = threadIdx.x;
    const int wid   = tid >> 6;
    const int lane  = tid & 63;

    __shared__ float red[3][16];
    __shared__ float invs[3];
    const float* base = hp + (size_t)img_i * 4 * 3072;

    float v[3];
    #pragma unroll
    for (int c = 0; c < 3; ++c) {
        const int idx = c * 1024 + tid;
        v[c] = base[idx] + base[3072 + idx] + base[2 * 3072 + idx] + base[3 * 3072 + idx];
    }

    // three independent wave reductions (ILP), one LDS round
    float t0 = v[0], t1 = v[1], t2 = v[2];
    #pragma unroll
    for (int off = 32; off; off >>= 1) {
        t0 += __shfl_down(t0, off);
        t1 += __shfl_down(t1, off);
        t2 += __shfl_down(t2, off);
    }
    if (lane == 0) { red[0][wid] = t0; red[1][wid] = t1; red[2][wid] = t2; }
    __syncthreads();
    if (tid < 3) {
        float s = 0.f;
        #pragma unroll
        for (int j = 0; j < 16; ++j) s += red[tid][j];
        invs[tid] = 1.0f / s;
    }
    __syncthreads();

    #pragma unroll
    for (int c = 0; c < 3; ++c)
        histT[xidx(c * 1024 + tid, img_i)] = sqrtf(v[c] * invs[c]);
}

// ---------------------------------------------------------------------------
// GEMM: y[o][b] += sum_{k in chunk} x[k][b] * W[o][k]   (atomic split-K)
// Wave = 8 outputs x 32 batches x chunk C. b = lane&31 (halves duplicate).
// W addresses are wave-uniform (readfirstlane) -> scalar s_load path.
// x loads: one float2 per lane = 256B coalesced per 2 k's.
// RELU applies relu to x on load (previous layer stored pre-activation).
// ---------------------------------------------------------------------------
template <int K, int N, int S, bool RELU>
__global__ __launch_bounds__(256) void gemm_atomic_k(const float* __restrict__ xT,
                                                     const float* __restrict__ W,
                                                     float* __restrict__ y)
{
    constexpr int C  = K / S;
    constexpr int NG = N / 8;

    const int wave = (blockIdx.x * 256 + threadIdx.x) >> 6;
    const int lane = threadIdx.x & 63;
    const int b    = lane & 31;
    const int o0   = __builtin_amdgcn_readfirstlane((wave % NG) * 8);
    const int k0   = __builtin_amdgcn_readfirstlane((wave / NG) * C);

    const float* Wr[8];
    #pragma unroll
    for (int j = 0; j < 8; ++j) Wr[j] = W + (size_t)(o0 + j) * K + k0;

    const float2* xp = reinterpret_cast<const float2*>(xT + (size_t)k0 * BATCH) + b;

    float acc[8] = {0.f, 0.f, 0.f, 0.f, 0.f, 0.f, 0.f, 0.f};

    #pragma unroll 4
    for (int kk2 = 0; kk2 < C / 2; ++kk2) {
        float2 v = xp[kk2 * BATCH];
        if (RELU) { v.x = fmaxf(v.x, 0.f); v.y = fmaxf(v.y, 0.f); }
        #pragma unroll
        for (int j = 0; j < 8; ++j) {
            acc[j] = fmaf(v.x, Wr[j][2 * kk2],     acc[j]);
            acc[j] = fmaf(v.y, Wr[j][2 * kk2 + 1], acc[j]);
        }
    }

    if (lane < 32) {
        #pragma unroll
        for (int j = 0; j < 8; ++j)
            atomicAdd(&y[xidx(o0 + j, b)], acc[j]);
    }
}

// ---------------------------------------------------------------------------
// L3: block-local split-K. One block per 8-output group; 4 waves each take a
// 128-k chunk; LDS reduce; bias + ReLU; write out[b][o] directly.
// ---------------------------------------------------------------------------
template <int K, int N>
__global__ __launch_bounds__(256) void linear_out_k(const float* __restrict__ xT,
                                                    const float* __restrict__ W,
                                                    const float* __restrict__ bias,
                                                    float* __restrict__ out)
{
    constexpr int C = K / 4;                 // 128
    const int og   = blockIdx.x;             // 32 o-groups
    const int w    = threadIdx.x >> 6;
    const int lane = threadIdx.x & 63;
    const int b    = lane & 31;
    const int o0   = og * 8;
    const int k0   = __builtin_amdgcn_readfirstlane(w * C);

    const float* Wr[8];
    #pragma unroll
    for (int j = 0; j < 8; ++j) Wr[j] = W + (size_t)(o0 + j) * K + k0;

    const float2* xp = reinterpret_cast<const float2*>(xT + (size_t)k0 * BATCH) + b;

    float acc[8] = {0.f, 0.f, 0.f, 0.f, 0.f, 0.f, 0.f, 0.f};

    #pragma unroll 4
    for (int kk2 = 0; kk2 < C / 2; ++kk2) {
        float2 v = xp[kk2 * BATCH];
        v.x = fmaxf(v.x, 0.f); v.y = fmaxf(v.y, 0.f);
        #pragma unroll
        for (int j = 0; j < 8; ++j) {
            acc[j] = fmaf(v.x, Wr[j][2 * kk2],     acc[j]);
            acc[j] = fmaf(v.y, Wr[j][2 * kk2 + 1], acc[j]);
        }
    }

    __shared__ float part[4][8][32];
    if (lane < 32) {
        #pragma unroll
        for (int j = 0; j < 8; ++j) part[w][j][b] = acc[j];
    }
    __syncthreads();

    const int j  = threadIdx.x >> 5;         // output within group
    const int b2 = threadIdx.x & 31;         // batch
    float s = part[0][j][b2] + part[1][j][b2] + part[2][j][b2] + part[3][j][b2]
            + bias[o0 + j];
    out[b2 * N + o0 + j] = fmaxf(s, 0.f);
}

// ---------------------------------------------------------------------------
extern "C" void kernel_launch(void* const* d_in, const int* in_sizes, int n_in,
                              void* d_out, int out_size, void* d_ws, size_t ws_size,
                              hipStream_t stream)
{
    const float* img = (const float*)d_in[0];
    const float* W1  = (const float*)d_in[1];
    const float* b1  = (const float*)d_in[2];
    const float* W2  = (const float*)d_in[3];
    const float* b2  = (const float*)d_in[4];
    const float* W3  = (const float*)d_in[5];
    const float* b3  = (const float*)d_in[6];
    float* out = (float*)d_out;

    float* ws = (float*)d_ws;
    float* hp    = ws;                      // [128][3072] hist partials
    float* histT = hp    + 128 * 3072;      // [3072][32] paired
    float* y1    = histT + 3072 * BATCH;    // [1024][32] paired
    float* y2    = y1    + 1024 * BATCH;    // [512][32] paired

    // hist partials + y1/y2 bias init (fused): 128 + 192 blocks
    hist_part_k<<<320, 256, 0, stream>>>(img, hp, b1, b2, y1, y2);
    hist_norm_k<<<BATCH, 1024, 0, stream>>>(hp, histT);

    // L1: 3072 -> 1024   (2048 waves, atomic split-K 16)
    gemm_atomic_k<3072, 1024, 16, false><<<512, 256, 0, stream>>>(histT, W1, y1);
    // L2: 1024 -> 512    (1024 waves, atomic split-K 16)
    gemm_atomic_k<1024,  512, 16, true ><<<256, 256, 0, stream>>>(y1, W2, y2);
    // L3: 512 -> 256     (32 blocks, block-local split-K, writes out[b][o])
    linear_out_k<512, 256><<<32, 256, 0, stream>>>(y2, W3, b3, out);
}

// Round 6
// 186.584 us; speedup vs baseline: 1.0438x; 1.0286x over previous
//
#include <hip/hip_runtime.h>
#include <math.h>

#define IMG_H 512
#define IMG_W 512
#define HWSZ (IMG_H * IMG_W)
#define BATCH 32

// paired activation layout: element (k, b) lives at (k>>1)*64 + b*2 + (k&1)
// so one float2 per lane (b) covers k and k+1 -> 256B coalesced wave load.
__device__ __forceinline__ size_t xidx(int k, int b) {
    return (size_t)(k >> 1) * 64 + b * 2 + (k & 1);
}

// ---------------------------------------------------------------------------
// Kernel 1: blocks 0..127   = partial histograms (4 blocks/image, 1 px/thread)
//           blocks 128..319 = bias init of y1 (32768) and y2 (16384), paired
// ---------------------------------------------------------------------------
__global__ __launch_bounds__(256) void hist_part_k(const float* __restrict__ img,
                                                   float* __restrict__ hp,
                                                   const float* __restrict__ b1,
                                                   const float* __restrict__ b2,
                                                   float* __restrict__ y1,
                                                   float* __restrict__ y2)
{
    if (blockIdx.x >= 128) {
        const int t = (blockIdx.x - 128) * 256 + threadIdx.x;   // [0, 49152)
        if (t < 32768) {
            const int o = ((t >> 6) << 1) | (t & 1);
            y1[t] = b1[o];
        } else {
            const int u = t - 32768;
            const int o = ((u >> 6) << 1) | (u & 1);
            y2[u] = b2[o];
        }
        return;
    }

    const int img_i = blockIdx.x >> 2;
    const int blk   = blockIdx.x & 3;
    const int tid   = threadIdx.x;

    __shared__ float hh[3072];
    for (int i = tid; i < 3072; i += 256) hh[i] = 0.f;
    __syncthreads();

    const int p  = blk * 256 + tid;          // downsampled pixel id 0..1023
    const int py = p >> 5;
    const int px = p & 31;
    const size_t base = (size_t)img_i * 3 * HWSZ + (size_t)(py * 16) * IMG_W + (size_t)(px * 16);

    const float r  = img[base];
    const float g  = img[base + HWSZ];
    const float bl = img[base + 2 * HWSZ];

    const bool valid = (r > 0.f) && (g > 0.f) && (bl > 0.f);

    const float LOc = (float)(-3.2 - (6.4 / 256.0) * 0.5);
    const float HIc = (float)( 3.2 - (6.4 / 256.0) * 0.5);
    const float BWc = (float)(((3.2 - (6.4 / 256.0) * 0.5) - (-3.2 - (6.4 / 256.0) * 0.5)) / 32.0);

    if (valid) {
        const float w  = sqrtf(r * r + g * g + bl * bl);
        const float lr = logf(r);
        const float lg = logf(g);
        const float lb = logf(bl);

        float us[3] = { lr - lb, lg - lb, lb - lg };
        float vs[3] = { lr - lg, lg - lr, lb - lr };

        #pragma unroll
        for (int i = 0; i < 3; ++i) {
            const float U = us[i];
            const float V = vs[i];
            if (U >= LOc && U <= HIc && V >= LOc && V <= HIc) {
                int iu = (int)floorf((U - LOc) / BWc); iu = iu < 31 ? iu : 31;
                int iv = (int)floorf((V - LOc) / BWc); iv = iv < 31 ? iv : 31;
                atomicAdd(&hh[i * 1024 + iu * 32 + iv], w);
            }
        }
    }
    __syncthreads();

    float* outp = hp + (size_t)blockIdx.x * 3072;
    for (int i = tid; i < 3072; i += 256) outp[i] = hh[i];
}

// ---------------------------------------------------------------------------
// Kernel 2: per-image normalize + sqrt, write paired-transposed histT.
// One block (1024 threads) per image; all 3 channels reduced concurrently.
// ---------------------------------------------------------------------------
__global__ __launch_bounds__(1024) void hist_norm_k(const float* __restrict__ hp,
                                                    float* __restrict__ histT)
{
    const int img_i = blockIdx.x;
    const int tid   = threadIdx.x;
    const int wid   = tid >> 6;
    const int lane  = tid & 63;

    __shared__ float red[3][16];
    __shared__ float invs[3];
    const float* base = hp + (size_t)img_i * 4 * 3072;

    float v[3];
    #pragma unroll
    for (int c = 0; c < 3; ++c) {
        const int idx = c * 1024 + tid;
        v[c] = base[idx] + base[3072 + idx] + base[2 * 3072 + idx] + base[3 * 3072 + idx];
    }

    float t0 = v[0], t1 = v[1], t2 = v[2];
    #pragma unroll
    for (int off = 32; off; off >>= 1) {
        t0 += __shfl_down(t0, off);
        t1 += __shfl_down(t1, off);
        t2 += __shfl_down(t2, off);
    }
    if (lane == 0) { red[0][wid] = t0; red[1][wid] = t1; red[2][wid] = t2; }
    __syncthreads();
    if (tid < 3) {
        float s = 0.f;
        #pragma unroll
        for (int j = 0; j < 16; ++j) s += red[tid][j];
        invs[tid] = 1.0f / s;
    }
    __syncthreads();

    #pragma unroll
    for (int c = 0; c < 3; ++c)
        histT[xidx(c * 1024 + tid, img_i)] = sqrtf(v[c] * invs[c]);
}

// ---------------------------------------------------------------------------
// GEMM: y[o][b] += sum_{k in chunk} x[k][b] * W[o][k]   (atomic split-K)
// Wave = 8 outputs x 32 batches x chunk C. b = lane&31 (halves duplicate).
// W addresses are wave-uniform (readfirstlane) -> scalar s_load path.
// x loads: one float2 per lane = 256B coalesced per 2 k's.
// RELU applies relu to x on load (previous layer stored pre-activation).
// ---------------------------------------------------------------------------
template <int K, int N, int S, bool RELU>
__global__ __launch_bounds__(256) void gemm_atomic_k(const float* __restrict__ xT,
                                                     const float* __restrict__ W,
                                                     float* __restrict__ y)
{
    constexpr int C  = K / S;
    constexpr int NG = N / 8;

    const int wave = (blockIdx.x * 256 + threadIdx.x) >> 6;
    const int lane = threadIdx.x & 63;
    const int b    = lane & 31;
    const int o0   = __builtin_amdgcn_readfirstlane((wave % NG) * 8);
    const int k0   = __builtin_amdgcn_readfirstlane((wave / NG) * C);

    const float* Wr[8];
    #pragma unroll
    for (int j = 0; j < 8; ++j) Wr[j] = W + (size_t)(o0 + j) * K + k0;

    const float2* xp = reinterpret_cast<const float2*>(xT + (size_t)k0 * BATCH) + b;

    float acc[8] = {0.f, 0.f, 0.f, 0.f, 0.f, 0.f, 0.f, 0.f};

    #pragma unroll 4
    for (int kk2 = 0; kk2 < C / 2; ++kk2) {
        float2 v = xp[kk2 * BATCH];
        if (RELU) { v.x = fmaxf(v.x, 0.f); v.y = fmaxf(v.y, 0.f); }
        #pragma unroll
        for (int j = 0; j < 8; ++j) {
            acc[j] = fmaf(v.x, Wr[j][2 * kk2],     acc[j]);
            acc[j] = fmaf(v.y, Wr[j][2 * kk2 + 1], acc[j]);
        }
    }

    if (lane < 32) {
        #pragma unroll
        for (int j = 0; j < 8; ++j)
            atomicAdd(&y[xidx(o0 + j, b)], acc[j]);
    }
}

// ---------------------------------------------------------------------------
// L3: block-local split-K. One block per 8-output group; 8 waves each take a
// 64-k chunk; LDS reduce; bias + ReLU; write out[b][o] directly.
// ---------------------------------------------------------------------------
template <int K, int N>
__global__ __launch_bounds__(512) void linear_out_k(const float* __restrict__ xT,
                                                    const float* __restrict__ W,
                                                    const float* __restrict__ bias,
                                                    float* __restrict__ out)
{
    constexpr int C = K / 8;                 // 64
    const int og   = blockIdx.x;             // 32 o-groups
    const int w    = threadIdx.x >> 6;       // wave 0..7
    const int lane = threadIdx.x & 63;
    const int b    = lane & 31;
    const int o0   = og * 8;
    const int k0   = __builtin_amdgcn_readfirstlane(w * C);

    const float* Wr[8];
    #pragma unroll
    for (int j = 0; j < 8; ++j) Wr[j] = W + (size_t)(o0 + j) * K + k0;

    const float2* xp = reinterpret_cast<const float2*>(xT + (size_t)k0 * BATCH) + b;

    float acc[8] = {0.f, 0.f, 0.f, 0.f, 0.f, 0.f, 0.f, 0.f};

    #pragma unroll 4
    for (int kk2 = 0; kk2 < C / 2; ++kk2) {
        float2 v = xp[kk2 * BATCH];
        v.x = fmaxf(v.x, 0.f); v.y = fmaxf(v.y, 0.f);
        #pragma unroll
        for (int j = 0; j < 8; ++j) {
            acc[j] = fmaf(v.x, Wr[j][2 * kk2],     acc[j]);
            acc[j] = fmaf(v.y, Wr[j][2 * kk2 + 1], acc[j]);
        }
    }

    __shared__ float part[8][8][32];
    if (lane < 32) {
        #pragma unroll
        for (int j = 0; j < 8; ++j) part[w][j][b] = acc[j];
    }
    __syncthreads();

    if (threadIdx.x < 256) {
        const int j  = threadIdx.x >> 5;     // output within group
        const int b2 = threadIdx.x & 31;     // batch
        float s = bias[o0 + j];
        #pragma unroll
        for (int i = 0; i < 8; ++i) s += part[i][j][b2];
        out[b2 * N + o0 + j] = fmaxf(s, 0.f);
    }
}

// ---------------------------------------------------------------------------
extern "C" void kernel_launch(void* const* d_in, const int* in_sizes, int n_in,
                              void* d_out, int out_size, void* d_ws, size_t ws_size,
                              hipStream_t stream)
{
    const float* img = (const float*)d_in[0];
    const float* W1  = (const float*)d_in[1];
    const float* b1  = (const float*)d_in[2];
    const float* W2  = (const float*)d_in[3];
    const float* b2  = (const float*)d_in[4];
    const float* W3  = (const float*)d_in[5];
    const float* b3  = (const float*)d_in[6];
    float* out = (float*)d_out;

    float* ws = (float*)d_ws;
    float* hp    = ws;                      // [128][3072] hist partials
    float* histT = hp    + 128 * 3072;      // [3072][32] paired
    float* y1    = histT + 3072 * BATCH;    // [1024][32] paired
    float* y2    = y1    + 1024 * BATCH;    // [512][32] paired

    // hist partials + y1/y2 bias init (fused): 128 + 192 blocks
    hist_part_k<<<320, 256, 0, stream>>>(img, hp, b1, b2, y1, y2);
    hist_norm_k<<<BATCH, 1024, 0, stream>>>(hp, histT);

    // L1: 3072 -> 1024   (4096 waves, atomic split-K 32, C=96)
    gemm_atomic_k<3072, 1024, 32, false><<<1024, 256, 0, stream>>>(histT, W1, y1);
    // L2: 1024 -> 512    (2048 waves, atomic split-K 32, C=32)
    gemm_atomic_k<1024,  512, 32, true ><<<512, 256, 0, stream>>>(y1, W2, y2);
    // L3: 512 -> 256     (32 blocks x 8 waves, block-local split-K, C=64)
    linear_out_k<512, 256><<<32, 512, 0, stream>>>(y2, W3, b3, out);
}